// Round 3
// baseline (146.301 us; speedup 1.0000x reference)
//
#include <hip/hip_runtime.h>
#include <float.h>

#define B_   2
#define F_   8192
#define Q_   4096
#define NC   128         // F-chunks
#define FC   (F_/NC)     // 64 triangles per chunk -> 6-bit local index in key
#define PTS  256         // threads per scan block
#define PPT  4           // points per thread in scan

typedef float f4u __attribute__((ext_vector_type(4), aligned(4)));
typedef unsigned int uint;

// clamp(x,0,1) -> single v_med3_f32
__device__ __forceinline__ float clamp01s(float x) {
    return fminf(fmaxf(x, 0.f), 1.f);
}

// ---------------------------------------------------------------------------
// Exact reference-order Ericson barycentrics. Contract OFF: every op rounds
// exactly like the numpy reference; op order matches term-for-term.
// jnp.select first-true-wins priority; _safe_div(n,d) = n/(d==0?1:d).
__device__ __forceinline__ void bary_uvw(
    float ax, float ay, float az,
    float bx, float by, float bz,
    float cx, float cy, float cz,
    float px, float py, float pz,
    float& u, float& v, float& w)
{
#pragma clang fp contract(off)
    float abx = bx - ax, aby = by - ay, abz = bz - az;
    float acx = cx - ax, acy = cy - ay, acz = cz - az;
    float apx = px - ax, apy = py - ay, apz = pz - az;
    float d1 = abx*apx + aby*apy + abz*apz;
    float d2 = acx*apx + acy*apy + acz*apz;
    float bpx = px - bx, bpy = py - by, bpz = pz - bz;
    float d3 = abx*bpx + aby*bpy + abz*bpz;
    float d4 = acx*bpx + acy*bpy + acz*bpz;
    float qx = px - cx, qy = py - cy, qz = pz - cz;
    float d5 = abx*qx + aby*qy + abz*qz;
    float d6 = acx*qx + acy*qy + acz*qz;
    float vc = d1*d4 - d3*d2;
    float vb = d5*d2 - d1*d6;
    float va = d3*d6 - d5*d4;

    bool c1 = (d1 <= 0.f) && (d2 <= 0.f);
    bool c2 = (d3 >= 0.f) && (d4 <= d3);
    bool c3 = (vc <= 0.f) && (d1 >= 0.f) && (d3 <= 0.f);
    bool c4 = (d6 >= 0.f) && (d5 <= d6);
    bool c5 = (vb <= 0.f) && (d2 >= 0.f) && (d6 <= 0.f);
    bool c6 = (va <= 0.f) && (d4 >= d3) && (d5 >= d6);

    bool e1 = c1;
    bool p1 = !c1;
    bool e2 = p1 && c2;
    bool p2 = p1 && !c2;
    bool e3 = p2 && c3;
    bool p3 = p2 && !c3;
    bool e4 = p3 && c4;
    bool p4 = p3 && !c4;
    bool e5 = p4 && c5;
    bool p5 = p4 && !c5;
    bool e6 = p5 && c6;

    float d43 = d4 - d3;
    float d56 = d5 - d6;
    float n  = e3 ? d1        : (e5 ? d2        : (e6 ? d43         : 1.f));
    float dd = e3 ? (d1 - d3) : (e5 ? (d2 - d6) : (e6 ? (d43 + d56) : (va + vb + vc)));
    dd = (dd == 0.f) ? 1.f : dd;   // _safe_div
    float t = n / dd;

    float vi = vb * t;
    float wi = vc * t;
    u = e1 ? 1.f : (e2 ? 0.f : (e3 ? 1.f - t : (e4 ? 0.f : (e5 ? 1.f - t : (e6 ? 0.f     : 1.f - vi - wi)))));
    v = e1 ? 0.f : (e2 ? 1.f : (e3 ? t       : (e4 ? 0.f : (e5 ? 0.f     : (e6 ? 1.f - t : vi)))));
    w = e1 ? 0.f : (e2 ? 0.f : (e3 ? 0.f     : (e4 ? 1.f : (e5 ? t       : (e6 ? t       : wi)))));
}

// ---------------------------------------------------------------------------
// Scan: pure-scalar cheap loop nominates top-2/chunk (sortable SIGNED int
// keys); TAIL exact-evaluates both nominees per point with the np-order
// contract-off formula reading RAW a,b,c from LDS (bit-identical inputs =>
// bit-identical d^2) and emits one (d_exact_bits, face) pair per
// (point, chunk). NO cheap-distance filtering anywhere (R5 lesson).
//
// Nomination math engineered for backend fusions: nested fma dots with
// precomputed -ab.a / -ac.a / -2a / a.a; clamp01 -> v_med3; 3-way min/max ->
// v_min3 / v_max3; a*b - c*d -> mul + fma(neg). Contraction ON here
// (nomination has rounding freedom; exact tail decides).
__global__ __launch_bounds__(PTS, 4) void scan_kernel(
    const float* __restrict__ tri, const float* __restrict__ pts,
    uint2* __restrict__ keys)
{
    constexpr int IM = ~(FC - 1);      // keep distance bits; low 6 bits = local face
    // per-tri 5 x float4 nomination constants:
    // c0 = (abx,aby,abz, -ab.a)   c1 = (acx,acy,acz, -ac.a)
    // c2 = (-2ax,-2ay,-2az, a.a)  c3 = (daa,dcc,dac, nn)
    // c4 = (1/daa, 1/dcc, 1/dbc, 1/nn)
    __shared__ float4 SC[FC * 5];
    __shared__ float4 SR[FC * 3];      // raw a,b,c per triangle for exact tail
    const int tid = threadIdx.x;
    const int pb = blockIdx.x, cb = blockIdx.y, bb = blockIdx.z;

    if (tid < FC) {   // one thread stages one triangle fully
        const float* g = tri + ((size_t)bb * F_ + (size_t)cb * FC + tid) * 9;
        float ax = g[0], ay = g[1], az = g[2];
        float bx = g[3], by = g[4], bz = g[5];
        float cx = g[6], cy = g[7], cz = g[8];
        float abx = bx - ax, aby = by - ay, abz = bz - az;
        float acx = cx - ax, acy = cy - ay, acz = cz - az;
        float daa = abx*abx + aby*aby + abz*abz;
        float dcc = acx*acx + acy*acy + acz*acz;
        float dac = abx*acx + aby*acy + abz*acz;
        float dbc = daa + dcc - 2.f*dac;
        float nn  = daa*dcc - dac*dac;
        SC[tid*5 + 0] = make_float4(abx, aby, abz, -(abx*ax + aby*ay + abz*az));
        SC[tid*5 + 1] = make_float4(acx, acy, acz, -(acx*ax + acy*ay + acz*az));
        SC[tid*5 + 2] = make_float4(-2.f*ax, -2.f*ay, -2.f*az, ax*ax + ay*ay + az*az);
        SC[tid*5 + 3] = make_float4(daa, dcc, dac, nn);
        SC[tid*5 + 4] = make_float4(1.f/daa, 1.f/dcc, 1.f/dbc, 1.f/nn);
        SR[tid*3 + 0] = make_float4(ax, ay, az, 0.f);
        SR[tid*3 + 1] = make_float4(bx, by, bz, 0.f);
        SR[tid*3 + 2] = make_float4(cx, cy, cz, 0.f);
    }
    __syncthreads();

    const int q0 = pb * (PTS * PPT) + tid * PPT;
    const float* p0 = pts + ((size_t)bb * Q_ + q0) * 3;
    f4u l0 = *(const f4u*)(p0);
    f4u l1 = *(const f4u*)(p0 + 4);
    f4u l2 = *(const f4u*)(p0 + 8);
    float pxs[4] = {l0.x, l0.w, l1.z, l2.y};
    float pys[4] = {l0.y, l1.x, l1.w, l2.z};
    float pzs[4] = {l0.z, l1.y, l2.x, l2.w};
    float pps[4];
    #pragma unroll
    for (int p = 0; p < 4; ++p)
        pps[p] = pxs[p]*pxs[p] + pys[p]*pys[p] + pzs[p]*pzs[p];

    int K0[4] = {0x7FFFFFFF, 0x7FFFFFFF, 0x7FFFFFFF, 0x7FFFFFFF};
    int K1[4] = {0x7FFFFFFF, 0x7FFFFFFF, 0x7FFFFFFF, 0x7FFFFFFF};

    #pragma unroll 2
    for (int fl = 0; fl < FC; ++fl) {
        float4 c0 = SC[fl*5 + 0];
        float4 c1 = SC[fl*5 + 1];
        float4 c2 = SC[fl*5 + 2];
        float4 c3 = SC[fl*5 + 3];
        float4 c4 = SC[fl*5 + 4];
        float daa = c3.x, dcc = c3.y, dac = c3.z, nn = c3.w;
        float kk  = daa - dac;
        float dbc = daa + dcc - 2.f*dac;

        #pragma unroll
        for (int p = 0; p < 4; ++p) {
            float px = pxs[p], py = pys[p], pz = pzs[p];
            float d1 = fmaf(c0.x, px, fmaf(c0.y, py, fmaf(c0.z, pz, c0.w)));
            float d2 = fmaf(c1.x, px, fmaf(c1.y, py, fmaf(c1.z, pz, c1.w)));
            float s  = fmaf(c2.x, px, fmaf(c2.y, py, fmaf(c2.z, pz, c2.w)));
            float app = s + pps[p];

            float t1 = d1*dcc - d2*dac;
            float t2 = d2*daa - d1*dac;
            float ts = t1 + t2;
            float t12n = nn - ts;                       // sign-equiv inside test
            float ins  = fminf(fminf(t1, t2), t12n);    // v_min3
            float sgr  = (d1*t1 + d2*t2) * c4.w;

            float td1 = d1 + d1;
            float tab = clamp01s(d1 * c4.x);            // v_med3
            float rab = tab * (td1 - tab*daa);
            float td2 = d2 + d2;
            float tac = clamp01s(d2 * c4.y);
            float rac = tac * (td2 - tac*dcc);
            float d43 = (d2 - d1) + kk;
            float sbc = clamp01s(d43 * c4.z);
            float rbc = (td1 - daa) + sbc * ((d43 + d43) - sbc*dbc);
            float rmax = fmaxf(fmaxf(rab, rac), rbc);   // v_max3

            float red = (ins >= 0.f) ? sgr : rmax;
            float d = app - red;

            int k = (__float_as_int(d) & IM) | fl;      // v_and_or_b32
            int m = max(K0[p], k);
            K0[p] = min(K0[p], k);
            K1[p] = min(K1[p], m);
        }
    }

    // TAIL: exact np-order eval of both nominees per point (raw coords from LDS)
    #pragma unroll
    for (int p = 0; p < 4; ++p) {
        float px = pxs[p], py = pys[p], pz = pzs[p];
        float dbest = FLT_MAX; int fbest = 0x7FFFFFFF;
        #pragma unroll
        for (int j = 0; j < 2; ++j) {
            int lf = (j == 0 ? K0[p] : K1[p]) & (FC - 1);
            float4 ra = SR[lf*3 + 0];
            float4 rb = SR[lf*3 + 1];
            float4 rc = SR[lf*3 + 2];
            float u, v, w;
            bary_uvw(ra.x, ra.y, ra.z, rb.x, rb.y, rb.z, rc.x, rc.y, rc.z,
                     px, py, pz, u, v, w);
            float d2v;
            {
#pragma clang fp contract(off)
                float cpx = u*ra.x + v*rb.x + w*rc.x;
                float cpy = u*ra.y + v*rb.y + w*rc.y;
                float cpz = u*ra.z + v*rb.z + w*rc.z;
                float dx = cpx - px, dy = cpy - py, dz = cpz - pz;
                d2v = dx*dx + dy*dy + dz*dz;
            }
            int face = cb * FC + lf;
            if (d2v < dbest || (d2v == dbest && face < fbest)) { dbest = d2v; fbest = face; }
        }
        // point-major [b][q][chunk]: finalize reads coalesced uint4
        keys[((size_t)bb * Q_ + q0 + p) * NC + cb] = make_uint2(__float_as_uint(dbest), (uint)fbest);
    }
}

// ---------------------------------------------------------------------------
// Finalize: one WAVE per point; lane l loads chunks 2l,2l+1 exact pairs
// (coalesced uint4), wave lex-(d,face) reduce == jnp.argmin first occurrence
// (true winner is the exact-min of its chunk's top-2 pair, so it is the
// chunk representative). Lane 0 epilogue, contract-off np-order.
__global__ __launch_bounds__(256) void finalize_kernel(
    const float* __restrict__ tri, const float* __restrict__ pts,
    const float* __restrict__ nrm, const float* __restrict__ cmp,
    const int* __restrict__ faces,
    const uint2* __restrict__ keys,
    float* __restrict__ out)
{
#pragma clang fp contract(off)
    const int lane = threadIdx.x & 63;
    const int t = blockIdx.x * 4 + (threadIdx.x >> 6);
    const int bb = t >> 12;            // Q_ = 4096

    uint4 K = ((const uint4*)keys)[(size_t)t * (NC/2) + lane];
    float dbest = __uint_as_float(K.x); int fbest = (int)K.y;
    float d1v   = __uint_as_float(K.z); int f1v   = (int)K.w;
    if (d1v < dbest || (d1v == dbest && f1v < fbest)) { dbest = d1v; fbest = f1v; }
    for (int off = 32; off > 0; off >>= 1) {
        float od = __shfl_down(dbest, off);
        int   of = __shfl_down(fbest, off);
        if (od < dbest || (od == dbest && of < fbest)) { dbest = od; fbest = of; }
    }
    if (lane != 0) return;

    const float* pp = pts + (size_t)t * 3;
    float px = pp[0], py = pp[1], pz = pp[2];

    const int bestf = fbest;
    const float* tg = tri + ((size_t)bb * F_ + bestf) * 9;
    const float* ng = nrm + ((size_t)bb * F_ + bestf) * 9;
    const float* cg = cmp + ((size_t)bb * F_ + bestf) * 9;
    f4u TA = *(const f4u*)(tg), TB = *(const f4u*)(tg + 4);
    float TC = tg[8];
    f4u NA = *(const f4u*)(ng), NB = *(const f4u*)(ng + 4);
    float NCs = ng[8];
    f4u CA = *(const f4u*)(cg), CB = *(const f4u*)(cg + 4);
    float CC = cg[8];

    float u, v, w;
    bary_uvw(TA.x, TA.y, TA.z, TA.w, TB.x, TB.y, TB.z, TB.w, TC,
             px, py, pz, u, v, w);
    u = fminf(fmaxf(u, 0.f), 1.f);
    v = fminf(fmaxf(v, 0.f), 1.f);
    w = fminf(fmaxf(w, 0.f), 1.f);

    float cpx = u * TA.x + v * TA.w + w * TB.z;
    float cpy = u * TA.y + v * TB.x + w * TB.w;
    float cpz = u * TA.z + v * TB.y + w * TC;
    float nx  = u * NA.x + v * NA.w + w * NB.z;
    float ny  = u * NA.y + v * NB.x + w * NB.w;
    float nz  = u * NA.z + v * NB.y + w * NCs;
    float mx  = u * CA.x + v * CA.w + w * CB.z;
    float my  = u * CA.y + v * CB.x + w * CB.w;
    float mz  = u * CA.z + v * CB.y + w * CC;

    const size_t S3 = (size_t)B_ * Q_ * 3;
    out[(size_t)t * 3 + 0] = cpx - px;
    out[(size_t)t * 3 + 1] = cpy - py;
    out[(size_t)t * 3 + 2] = cpz - pz;
    out[S3 + (size_t)t * 3 + 0] = nx;
    out[S3 + (size_t)t * 3 + 1] = ny;
    out[S3 + (size_t)t * 3 + 2] = nz;
    out[2 * S3 + (size_t)t * 3 + 0] = mx;
    out[2 * S3 + (size_t)t * 3 + 1] = my;
    out[2 * S3 + (size_t)t * 3 + 2] = mz;

    int k = 0; float mm = u;
    if (v > mm) { mm = v; k = 1; }
    if (w > mm) { k = 2; }
    out[3 * S3 + t] = (float)faces[((size_t)bb * F_ + bestf) * 3 + k];
}

extern "C" void kernel_launch(void* const* d_in, const int* in_sizes, int n_in,
                              void* d_out, int out_size, void* d_ws, size_t ws_size,
                              hipStream_t stream) {
    const float* tri   = (const float*)d_in[0];
    const float* pts   = (const float*)d_in[1];
    const float* nrm   = (const float*)d_in[2];
    const float* cmp   = (const float*)d_in[3];
    const int*   faces = (const int*)d_in[4];
    float* out = (float*)d_out;

    uint2* keys = (uint2*)d_ws;   // [B][Q][NC] exact (d_bits, face) per chunk

    dim3 g1(Q_ / (PTS * PPT), NC, B_);
    scan_kernel<<<g1, PTS, 0, stream>>>(tri, pts, keys);
    finalize_kernel<<<(B_ * Q_) / 4, 256, 0, stream>>>(
        tri, pts, nrm, cmp, faces, keys, out);
}

// Round 4
// 145.669 us; speedup vs baseline: 1.0043x; 1.0043x over previous
//
#include <hip/hip_runtime.h>
#include <float.h>

#define B_   2
#define F_   8192
#define Q_   4096
#define NC   128         // F-chunks
#define FC   (F_/NC)     // 64 triangles per chunk -> 6-bit local index in key
#define PTS  256         // threads per scan block
#define PPT  2           // points per thread in scan (grid 2048 blocks = 8/CU)

typedef float f4u __attribute__((ext_vector_type(4), aligned(4)));
typedef float f2u __attribute__((ext_vector_type(2), aligned(8)));
typedef unsigned int uint;

// clamp(x,0,1)
__device__ __forceinline__ float clamp01s(float x) {
    return fminf(fmaxf(x, 0.f), 1.f);
}

// ---------------------------------------------------------------------------
// Exact reference-order Ericson barycentrics. Contract OFF: every op rounds
// exactly like the numpy reference; op order matches term-for-term.
// jnp.select first-true-wins priority; _safe_div(n,d) = n/(d==0?1:d).
__device__ __forceinline__ void bary_uvw(
    float ax, float ay, float az,
    float bx, float by, float bz,
    float cx, float cy, float cz,
    float px, float py, float pz,
    float& u, float& v, float& w)
{
#pragma clang fp contract(off)
    float abx = bx - ax, aby = by - ay, abz = bz - az;
    float acx = cx - ax, acy = cy - ay, acz = cz - az;
    float apx = px - ax, apy = py - ay, apz = pz - az;
    float d1 = abx*apx + aby*apy + abz*apz;
    float d2 = acx*apx + acy*apy + acz*apz;
    float bpx = px - bx, bpy = py - by, bpz = pz - bz;
    float d3 = abx*bpx + aby*bpy + abz*bpz;
    float d4 = acx*bpx + acy*bpy + acz*bpz;
    float qx = px - cx, qy = py - cy, qz = pz - cz;
    float d5 = abx*qx + aby*qy + abz*qz;
    float d6 = acx*qx + acy*qy + acz*qz;
    float vc = d1*d4 - d3*d2;
    float vb = d5*d2 - d1*d6;
    float va = d3*d6 - d5*d4;

    bool c1 = (d1 <= 0.f) && (d2 <= 0.f);
    bool c2 = (d3 >= 0.f) && (d4 <= d3);
    bool c3 = (vc <= 0.f) && (d1 >= 0.f) && (d3 <= 0.f);
    bool c4 = (d6 >= 0.f) && (d5 <= d6);
    bool c5 = (vb <= 0.f) && (d2 >= 0.f) && (d6 <= 0.f);
    bool c6 = (va <= 0.f) && (d4 >= d3) && (d5 >= d6);

    bool e1 = c1;
    bool p1 = !c1;
    bool e2 = p1 && c2;
    bool p2 = p1 && !c2;
    bool e3 = p2 && c3;
    bool p3 = p2 && !c3;
    bool e4 = p3 && c4;
    bool p4 = p3 && !c4;
    bool e5 = p4 && c5;
    bool p5 = p4 && !c5;
    bool e6 = p5 && c6;

    float d43 = d4 - d3;
    float d56 = d5 - d6;
    float n  = e3 ? d1        : (e5 ? d2        : (e6 ? d43         : 1.f));
    float dd = e3 ? (d1 - d3) : (e5 ? (d2 - d6) : (e6 ? (d43 + d56) : (va + vb + vc)));
    dd = (dd == 0.f) ? 1.f : dd;   // _safe_div
    float t = n / dd;

    float vi = vb * t;
    float wi = vc * t;
    u = e1 ? 1.f : (e2 ? 0.f : (e3 ? 1.f - t : (e4 ? 0.f : (e5 ? 1.f - t : (e6 ? 0.f     : 1.f - vi - wi)))));
    v = e1 ? 0.f : (e2 ? 1.f : (e3 ? t       : (e4 ? 0.f : (e5 ? 0.f     : (e6 ? 1.f - t : vi)))));
    w = e1 ? 0.f : (e2 ? 0.f : (e3 ? 0.f     : (e4 ? 1.f : (e5 ? t       : (e6 ? t       : wi)))));
}

// ---------------------------------------------------------------------------
// Precompute: 6 x float4 nomination constants per triangle (96 B):
// T0 = (abx,aby,abz, -ab.a)   T1 = (acx,acy,acz, -ac.a)
// T2 = (-2ax,-2ay,-2az, a.a)  T3 = (daa, dcc, -dac, nn)
// T4 = (1/daa, 1/dcc, 1/dbc, 1/nn)   T5 = (daa-dac, dbc, 0, 0)
__global__ void precompute_kernel(const float* __restrict__ tri,
                                  float4* __restrict__ cons)
{
    int i = blockIdx.x * blockDim.x + threadIdx.x;
    if (i >= B_ * F_) return;
    const float* g = tri + (size_t)i * 9;
    float ax = g[0], ay = g[1], az = g[2];
    float bx = g[3], by = g[4], bz = g[5];
    float cx = g[6], cy = g[7], cz = g[8];
    float abx = bx - ax, aby = by - ay, abz = bz - az;
    float acx = cx - ax, acy = cy - ay, acz = cz - az;
    float daa = abx*abx + aby*aby + abz*abz;
    float dcc = acx*acx + acy*acy + acz*acz;
    float dac = abx*acx + aby*acy + abz*acz;
    float dbc = daa + dcc - 2.f*dac;
    float nn  = daa*dcc - dac*dac;
    float4* o = cons + (size_t)i * 6;
    o[0] = make_float4(abx, aby, abz, -(abx*ax + aby*ay + abz*az));
    o[1] = make_float4(acx, acy, acz, -(acx*ax + acy*ay + acz*az));
    o[2] = make_float4(-2.f*ax, -2.f*ay, -2.f*az, ax*ax + ay*ay + az*az);
    o[3] = make_float4(daa, dcc, -dac, nn);
    o[4] = make_float4(1.f/daa, 1.f/dcc, 1.f/dbc, 1.f/nn);
    o[5] = make_float4(daa - dac, dbc, 0.f, 0.f);
}

// ---------------------------------------------------------------------------
// Scan: NO LDS, NO syncthreads. Per-triangle constants come from the
// precomputed table via wave-uniform addresses (-> scalar/SMEM loads).
// Cheap loop nominates top-2/chunk (sortable SIGNED int keys); TAIL
// exact-evaluates both nominees per point with the np-order contract-off
// formula reading RAW a,b,c straight from global tri (bit-identical inputs
// => bit-identical d^2). NO cheap-distance filtering anywhere (R5 lesson).
__global__ __launch_bounds__(PTS, 8) void scan_kernel(
    const float* __restrict__ tri, const float* __restrict__ pts,
    const float4* __restrict__ cons, uint2* __restrict__ keys)
{
    constexpr int IM = ~(FC - 1);      // keep distance bits; low 6 bits = local face
    const int tid = threadIdx.x;
    const int pb = blockIdx.x, cb = blockIdx.y, bb = blockIdx.z;

    const int q0 = pb * (PTS * PPT) + tid * PPT;
    const float* p0 = pts + ((size_t)bb * Q_ + q0) * 3;    // 24B-aligned (q0 even)
    f2u m0 = *(const f2u*)(p0);
    f2u m1 = *(const f2u*)(p0 + 2);
    f2u m2 = *(const f2u*)(p0 + 4);
    float px0 = m0.x, py0 = m0.y, pz0 = m1.x;
    float px1 = m1.y, py1 = m2.x, pz1 = m2.y;
    float pp0 = px0*px0 + py0*py0 + pz0*pz0;
    float pp1 = px1*px1 + py1*py1 + pz1*pz1;

    const float4* ct = cons + ((size_t)bb * F_ + (size_t)cb * FC) * 6;

    int K00 = 0x7FFFFFFF, K01 = 0x7FFFFFFF;
    int K10 = 0x7FFFFFFF, K11 = 0x7FFFFFFF;

    #pragma unroll 2
    for (int fl = 0; fl < FC; ++fl) {
        float4 T0 = ct[fl*6 + 0];
        float4 T1 = ct[fl*6 + 1];
        float4 T2 = ct[fl*6 + 2];
        float4 T3 = ct[fl*6 + 3];
        float4 T4 = ct[fl*6 + 4];
        float4 T5 = ct[fl*6 + 5];

        // ---- point 0
        {
            float d1 = fmaf(T0.x, px0, fmaf(T0.y, py0, fmaf(T0.z, pz0, T0.w)));
            float d2 = fmaf(T1.x, px0, fmaf(T1.y, py0, fmaf(T1.z, pz0, T1.w)));
            float s  = fmaf(T2.x, px0, fmaf(T2.y, py0, fmaf(T2.z, pz0, T2.w)));
            float app = s + pp0;
            float t1 = fmaf(d2, T3.z, d1 * T3.y);    // d1*dcc - d2*dac
            float t2 = fmaf(d1, T3.z, d2 * T3.x);    // d2*daa - d1*dac
            float t12n = T3.w - (t1 + t2);
            float ins  = fminf(fminf(t1, t2), t12n);
            float sgr  = fmaf(d2, t2, d1 * t1) * T4.w;
            float td1 = d1 + d1;
            float tab = clamp01s(d1 * T4.x);
            float rab = tab * fmaf(-tab, T3.x, td1);
            float td2 = d2 + d2;
            float tac = clamp01s(d2 * T4.y);
            float rac = tac * fmaf(-tac, T3.y, td2);
            float d43 = (d2 - d1) + T5.x;
            float sbc = clamp01s(d43 * T4.z);
            float rbc = (td1 - T3.x) + sbc * fmaf(-sbc, T5.y, d43 + d43);
            float rmax = fmaxf(fmaxf(rab, rac), rbc);
            float red = (ins >= 0.f) ? sgr : rmax;
            float dd = app - red;
            int k = (__float_as_int(dd) & IM) | fl;
            int m = max(K00, k);
            K00 = min(K00, k);
            K01 = min(K01, m);
        }
        // ---- point 1
        {
            float d1 = fmaf(T0.x, px1, fmaf(T0.y, py1, fmaf(T0.z, pz1, T0.w)));
            float d2 = fmaf(T1.x, px1, fmaf(T1.y, py1, fmaf(T1.z, pz1, T1.w)));
            float s  = fmaf(T2.x, px1, fmaf(T2.y, py1, fmaf(T2.z, pz1, T2.w)));
            float app = s + pp1;
            float t1 = fmaf(d2, T3.z, d1 * T3.y);
            float t2 = fmaf(d1, T3.z, d2 * T3.x);
            float t12n = T3.w - (t1 + t2);
            float ins  = fminf(fminf(t1, t2), t12n);
            float sgr  = fmaf(d2, t2, d1 * t1) * T4.w;
            float td1 = d1 + d1;
            float tab = clamp01s(d1 * T4.x);
            float rab = tab * fmaf(-tab, T3.x, td1);
            float td2 = d2 + d2;
            float tac = clamp01s(d2 * T4.y);
            float rac = tac * fmaf(-tac, T3.y, td2);
            float d43 = (d2 - d1) + T5.x;
            float sbc = clamp01s(d43 * T4.z);
            float rbc = (td1 - T3.x) + sbc * fmaf(-sbc, T5.y, d43 + d43);
            float rmax = fmaxf(fmaxf(rab, rac), rbc);
            float red = (ins >= 0.f) ? sgr : rmax;
            float dd = app - red;
            int k = (__float_as_int(dd) & IM) | fl;
            int m = max(K10, k);
            K10 = min(K10, k);
            K11 = min(K11, m);
        }
    }

    // TAIL: exact np-order eval of both nominees per point, raw coords from
    // global tri (bit-identical inputs => bit-identical d^2 vs reference).
    float pxs[2] = {px0, px1};
    float pys[2] = {py0, py1};
    float pzs[2] = {pz0, pz1};
    int kk0[2] = {K00, K10};
    int kk1[2] = {K01, K11};

    #pragma unroll
    for (int p = 0; p < 2; ++p) {
        float px = pxs[p], py = pys[p], pz = pzs[p];
        float dbest = FLT_MAX; int fbest = 0x7FFFFFFF;
        #pragma unroll
        for (int j = 0; j < 2; ++j) {
            int lf = (j == 0 ? kk0[p] : kk1[p]) & (FC - 1);
            const float* tg = tri + ((size_t)bb * F_ + (size_t)cb * FC + lf) * 9;
            f4u ra4 = *(const f4u*)(tg);
            f4u rb4 = *(const f4u*)(tg + 4);
            float rc8 = tg[8];
            float u, v, w;
            bary_uvw(ra4.x, ra4.y, ra4.z, ra4.w, rb4.x, rb4.y,
                     rb4.z, rb4.w, rc8, px, py, pz, u, v, w);
            float d2v;
            {
#pragma clang fp contract(off)
                float cpx = u*ra4.x + v*ra4.w + w*rb4.z;
                float cpy = u*ra4.y + v*rb4.x + w*rb4.w;
                float cpz = u*ra4.z + v*rb4.y + w*rc8;
                float dx = cpx - px, dy = cpy - py, dz = cpz - pz;
                d2v = dx*dx + dy*dy + dz*dz;
            }
            int face = cb * FC + lf;
            if (d2v < dbest || (d2v == dbest && face < fbest)) { dbest = d2v; fbest = face; }
        }
        // point-major [b][q][chunk]: finalize reads coalesced uint4
        keys[((size_t)bb * Q_ + q0 + p) * NC + cb] = make_uint2(__float_as_uint(dbest), (uint)fbest);
    }
}

// ---------------------------------------------------------------------------
// Finalize: one WAVE per point; lane l loads chunks 2l,2l+1 exact pairs
// (coalesced uint4), wave lex-(d,face) reduce == jnp.argmin first occurrence
// (true winner is the exact-min of its chunk's top-2 pair, so it is the
// chunk representative). Lane 0 epilogue, contract-off np-order.
__global__ __launch_bounds__(256) void finalize_kernel(
    const float* __restrict__ tri, const float* __restrict__ pts,
    const float* __restrict__ nrm, const float* __restrict__ cmp,
    const int* __restrict__ faces,
    const uint2* __restrict__ keys,
    float* __restrict__ out)
{
#pragma clang fp contract(off)
    const int lane = threadIdx.x & 63;
    const int t = blockIdx.x * 4 + (threadIdx.x >> 6);
    const int bb = t >> 12;            // Q_ = 4096

    uint4 K = ((const uint4*)keys)[(size_t)t * (NC/2) + lane];
    float dbest = __uint_as_float(K.x); int fbest = (int)K.y;
    float d1v   = __uint_as_float(K.z); int f1v   = (int)K.w;
    if (d1v < dbest || (d1v == dbest && f1v < fbest)) { dbest = d1v; fbest = f1v; }
    for (int off = 32; off > 0; off >>= 1) {
        float od = __shfl_down(dbest, off);
        int   of = __shfl_down(fbest, off);
        if (od < dbest || (od == dbest && of < fbest)) { dbest = od; fbest = of; }
    }
    if (lane != 0) return;

    const float* pp = pts + (size_t)t * 3;
    float px = pp[0], py = pp[1], pz = pp[2];

    const int bestf = fbest;
    const float* tg = tri + ((size_t)bb * F_ + bestf) * 9;
    const float* ng = nrm + ((size_t)bb * F_ + bestf) * 9;
    const float* cg = cmp + ((size_t)bb * F_ + bestf) * 9;
    f4u TA = *(const f4u*)(tg), TB = *(const f4u*)(tg + 4);
    float TC = tg[8];
    f4u NA = *(const f4u*)(ng), NB = *(const f4u*)(ng + 4);
    float NCs = ng[8];
    f4u CA = *(const f4u*)(cg), CB = *(const f4u*)(cg + 4);
    float CC = cg[8];

    float u, v, w;
    bary_uvw(TA.x, TA.y, TA.z, TA.w, TB.x, TB.y, TB.z, TB.w, TC,
             px, py, pz, u, v, w);
    u = fminf(fmaxf(u, 0.f), 1.f);
    v = fminf(fmaxf(v, 0.f), 1.f);
    w = fminf(fmaxf(w, 0.f), 1.f);

    float cpx = u * TA.x + v * TA.w + w * TB.z;
    float cpy = u * TA.y + v * TB.x + w * TB.w;
    float cpz = u * TA.z + v * TB.y + w * TC;
    float nx  = u * NA.x + v * NA.w + w * NB.z;
    float ny  = u * NA.y + v * NB.x + w * NB.w;
    float nz  = u * NA.z + v * NB.y + w * NCs;
    float mx  = u * CA.x + v * CA.w + w * CB.z;
    float my  = u * CA.y + v * CB.x + w * CB.w;
    float mz  = u * CA.z + v * CB.y + w * CC;

    const size_t S3 = (size_t)B_ * Q_ * 3;
    out[(size_t)t * 3 + 0] = cpx - px;
    out[(size_t)t * 3 + 1] = cpy - py;
    out[(size_t)t * 3 + 2] = cpz - pz;
    out[S3 + (size_t)t * 3 + 0] = nx;
    out[S3 + (size_t)t * 3 + 1] = ny;
    out[S3 + (size_t)t * 3 + 2] = nz;
    out[2 * S3 + (size_t)t * 3 + 0] = mx;
    out[2 * S3 + (size_t)t * 3 + 1] = my;
    out[2 * S3 + (size_t)t * 3 + 2] = mz;

    int k = 0; float mm = u;
    if (v > mm) { mm = v; k = 1; }
    if (w > mm) { k = 2; }
    out[3 * S3 + t] = (float)faces[((size_t)bb * F_ + bestf) * 3 + k];
}

extern "C" void kernel_launch(void* const* d_in, const int* in_sizes, int n_in,
                              void* d_out, int out_size, void* d_ws, size_t ws_size,
                              hipStream_t stream) {
    const float* tri   = (const float*)d_in[0];
    const float* pts   = (const float*)d_in[1];
    const float* nrm   = (const float*)d_in[2];
    const float* cmp   = (const float*)d_in[3];
    const int*   faces = (const int*)d_in[4];
    float* out = (float*)d_out;

    uint2*  keys = (uint2*)d_ws;   // [B][Q][NC] exact (d_bits, face) per chunk: 8 MiB
    float4* cons = (float4*)((char*)d_ws + (size_t)B_ * Q_ * NC * sizeof(uint2));  // 1.5 MiB

    precompute_kernel<<<(B_ * F_ + 255) / 256, 256, 0, stream>>>(tri, cons);

    dim3 g1(Q_ / (PTS * PPT), NC, B_);   // (8, 128, 2) = 2048 blocks = 8/CU
    scan_kernel<<<g1, PTS, 0, stream>>>(tri, pts, cons, keys);
    finalize_kernel<<<(B_ * Q_) / 4, 256, 0, stream>>>(
        tri, pts, nrm, cmp, faces, keys, out);
}